// Round 1
// baseline (133.101 us; speedup 1.0000x reference)
//
#include <hip/hip_runtime.h>

// NCC (local normalized cross-correlation) loss, 9x9x9 window, zero-pad.
// Volume: [1,1,128,160,192] f32. Output: scalar f32 = 1 - mean(cc).
//
// Strategy: separable box filter.
//   pass1: along W (contiguous). Reads I,J; writes 5 channels (I,J,I2,J2,IJ)
//          box-summed along W into d_ws.
//   pass2: along H, in-place per-(d,channel,w-tile) block via LDS tile.
//   pass3: along D, fused with cc computation + global reduction (atomicAdd).
//   finalize: out = 1 - acc/N.
// Workspace: 5*N*4 bytes channels + 1 float accumulator = ~78.6 MB.

#define D_ 128
#define H_ 160
#define W_ 192
#define N_ (D_ * H_ * W_)          // 3,932,160
#define WIN_INV (1.0f / 729.0f)

__global__ __launch_bounds__(192) void ncc_pass1(const float* __restrict__ I,
                                                 const float* __restrict__ J,
                                                 float* __restrict__ ws,
                                                 float* __restrict__ acc) {
    __shared__ float sI[W_];
    __shared__ float sJ[W_];
    const int line = blockIdx.x;            // d*H_ + h
    const int w = threadIdx.x;
    const int base = line * W_;
    sI[w] = I[base + w];
    sJ[w] = J[base + w];
    if (line == 0 && w == 0) *acc = 0.0f;   // zero reduction accumulator
    __syncthreads();
    float s1 = 0.f, s2 = 0.f, s3 = 0.f, s4 = 0.f, s5 = 0.f;
#pragma unroll
    for (int j = -4; j <= 4; ++j) {
        int idx = w + j;
        if (idx >= 0 && idx < W_) {
            float a = sI[idx], b = sJ[idx];
            s1 += a; s2 += b; s3 += a * a; s4 += b * b; s5 += a * b;
        }
    }
    ws[0 * N_ + base + w] = s1;
    ws[1 * N_ + base + w] = s2;
    ws[2 * N_ + base + w] = s3;
    ws[3 * N_ + base + w] = s4;
    ws[4 * N_ + base + w] = s5;
}

// One block per (d, channel, 64-wide w-tile). In-place along H.
__global__ __launch_bounds__(256) void ncc_pass2(float* __restrict__ ws) {
    __shared__ float tile[H_][64];          // 40 KB
    const int b = blockIdx.x;
    const int wt = b % (W_ / 64);
    const int c = (b / (W_ / 64)) % 5;
    const int d = b / ((W_ / 64) * 5);
    const int cbase = c * N_ + d * H_ * W_ + wt * 64;
    for (int i = threadIdx.x; i < H_ * 64; i += 256) {
        int h = i >> 6, w = i & 63;
        tile[h][w] = ws[cbase + h * W_ + w];
    }
    __syncthreads();
    for (int i = threadIdx.x; i < H_ * 64; i += 256) {
        int h = i >> 6, w = i & 63;
        float s = 0.f;
#pragma unroll
        for (int j = -4; j <= 4; ++j) {
            int hh = h + j;
            if (hh >= 0 && hh < H_) s += tile[hh][w];
        }
        ws[cbase + h * W_ + w] = s;         // block owns this region: safe
    }
}

// One block per (h, 16-wide w-tile). D-axis box sum fused with cc + reduce.
__global__ __launch_bounds__(256) void ncc_pass3(const float* __restrict__ ws,
                                                 float* __restrict__ acc) {
    __shared__ float tile[5][D_][16];       // 40 KB
    const int b = blockIdx.x;
    const int wt = b % (W_ / 16);
    const int h = b / (W_ / 16);
    const int base = h * W_ + wt * 16;
#pragma unroll
    for (int c = 0; c < 5; ++c) {
        for (int i = threadIdx.x; i < D_ * 16; i += 256) {
            int d = i >> 4, w = i & 15;
            tile[c][d][w] = ws[c * N_ + base + d * (H_ * W_) + w];
        }
    }
    __syncthreads();
    float sum = 0.f;
    for (int i = threadIdx.x; i < D_ * 16; i += 256) {
        int d = i >> 4, w = i & 15;
        float S1 = 0.f, S2 = 0.f, S3 = 0.f, S4 = 0.f, S5 = 0.f;
#pragma unroll
        for (int j = -4; j <= 4; ++j) {
            int dd = d + j;
            if (dd >= 0 && dd < D_) {
                S1 += tile[0][dd][w];
                S2 += tile[1][dd][w];
                S3 += tile[2][dd][w];
                S4 += tile[3][dd][w];
                S5 += tile[4][dd][w];
            }
        }
        float cross = S5 - S2 * S1 * WIN_INV;
        float Ivar  = S3 - S1 * S1 * WIN_INV;
        float Jvar  = S4 - S2 * S2 * WIN_INV;
        float cc = cross * cross / (Ivar * Jvar + 1e-5f);
        sum += cc;
    }
    // wave reduce (64 lanes) then cross-wave via LDS
    for (int off = 32; off; off >>= 1) sum += __shfl_down(sum, off, 64);
    __shared__ float wsum[4];
    const int lane = threadIdx.x & 63, wv = threadIdx.x >> 6;
    if (lane == 0) wsum[wv] = sum;
    __syncthreads();
    if (threadIdx.x == 0) {
        atomicAdd(acc, wsum[0] + wsum[1] + wsum[2] + wsum[3]);
    }
}

__global__ void ncc_finalize(const float* __restrict__ acc,
                             float* __restrict__ out) {
    out[0] = 1.0f - acc[0] * (1.0f / (float)N_);
}

extern "C" void kernel_launch(void* const* d_in, const int* in_sizes, int n_in,
                              void* d_out, int out_size, void* d_ws, size_t ws_size,
                              hipStream_t stream) {
    const float* I = (const float*)d_in[0];   // y_true
    const float* J = (const float*)d_in[1];   // y_pred
    float* ws = (float*)d_ws;                  // 5 channels of N_ floats
    float* acc = ws + 5 * N_;                  // 1-float accumulator
    float* out = (float*)d_out;

    ncc_pass1<<<D_ * H_, 192, 0, stream>>>(I, J, ws, acc);
    ncc_pass2<<<D_ * 5 * (W_ / 64), 256, 0, stream>>>(ws);
    ncc_pass3<<<H_ * (W_ / 16), 256, 0, stream>>>(ws, acc);
    ncc_finalize<<<1, 1, 0, stream>>>(acc, out);
}